// Round 2
// baseline (496.310 us; speedup 1.0000x reference)
//
#include <hip/hip_runtime.h>

#define N_TOT 65536
#define K_CB  2048
#define D_DIM 256
#define HW    4096       // H*W
#define DHW   1048576    // D*H*W

typedef _Float16 half8 __attribute__((ext_vector_type(8)));
typedef _Float16 half4v __attribute__((ext_vector_type(4)));
typedef float f32x16 __attribute__((ext_vector_type(16)));

// ws layout (4-byte element offsets):
//   cb2      [0, 2048)          float (np-pairwise ||c_k||^2)
//   counts   [2048, 4096)       int
//   sse      [4096]             float
//   z2       [4352, 69888)      float (np-pairwise ||z_n||^2)
//   rowmin_g [69888, 200960)    u64 x 65536
//   c_hi     [200960, 463104)   fp16 x 524288  (codebook * 2^14, hi)
//   c_lo     [463104, 725248)   fp16 x 524288  (lo)
// z splits live in d_out[0..16777216) floats (overwritten later by q):
//   z_hi = (fp16*)d_out  [65536][256] row-major, z * 2^11 hi;  z_lo follows.

__device__ __forceinline__ void gload_lds16(const void* g, void* l) {
    __builtin_amdgcn_global_load_lds((const __attribute__((address_space(1))) void*)g,
                                     (__attribute__((address_space(3))) void*)l, 16, 0, 0);
}

// ---------- codebook norms (np-pairwise, verified exact) + zero counts/sse ----------
__device__ __forceinline__ float pw128_sq(const float* __restrict__ base, int stride) {
    #pragma clang fp contract(off)
    float r[8];
    #pragma unroll
    for (int j = 0; j < 8; ++j) { float v = base[j * stride]; r[j] = v * v; }
    for (int i = 8; i < 128; i += 8) {
        #pragma unroll
        for (int j = 0; j < 8; ++j) { float v = base[(i + j) * stride]; r[j] += v * v; }
    }
    return ((r[0] + r[1]) + (r[2] + r[3])) + ((r[4] + r[5]) + (r[6] + r[7]));
}

__global__ void cbnorm_zero_kernel(const float* __restrict__ cb, float* __restrict__ cb2,
                                   int* __restrict__ counts, float* __restrict__ sse) {
    #pragma clang fp contract(off)
    int k = blockIdx.x * 256 + threadIdx.x;
    const float* row = cb + (size_t)k * D_DIM;
    cb2[k] = pw128_sq(row, 1) + pw128_sq(row + 128, 1);
    counts[k] = 0;
    if (k == 0) *sse = 0.f;
}

__global__ void split_c_kernel(const float* __restrict__ cb,
                               _Float16* __restrict__ ch, _Float16* __restrict__ cl) {
    int e = (blockIdx.x * 256 + threadIdx.x) * 4;
    float4 v = *(const float4*)(cb + e);
    float xs[4] = {v.x, v.y, v.z, v.w};
    half4v hh, hl;
    #pragma unroll
    for (int u = 0; u < 4; ++u) {
        float x = xs[u] * 16384.0f;                  // 2^14 exact
        _Float16 hv = (_Float16)x;
        hh[u] = hv;
        hl[u] = (_Float16)(x - (float)hv);           // exact sub, then RTNE
    }
    *(half4v*)(ch + e) = hh;
    *(half4v*)(cl + e) = hl;
}

// ---------- fused: z transpose+split, np-exact z2, rowmin_g init ----------
// Block: 32 rows x 256 d. 2048 blocks x 256 threads.
__global__ void fused_z_kernel(const float* __restrict__ z,
                               _Float16* __restrict__ zh, _Float16* __restrict__ zl,
                               float* __restrict__ z2,
                               unsigned long long* __restrict__ rowmin_g) {
    __shared__ __align__(16) float lt[256 * 33];   // lt[d][n], pad stride 33
    __shared__ float rj[512];                      // [n(32)][half(2)][j(8)]
    __shared__ float hh[64];                       // [half(2)][n(32)]
    int t = threadIdx.x;
    int n0 = blockIdx.x * 32;
    int b = n0 >> 12, s0 = n0 & 4095;
    const float* zb = z + (size_t)b * DHW + s0;

    #pragma unroll
    for (int v = 0; v < 8; ++v) {                  // 2048 float4 loads
        int f = v * 256 + t;
        int d = f >> 3, nch = f & 7;
        float4 val = *(const float4*)(zb + (size_t)d * HW + nch * 4);
        lt[d * 33 + nch * 4 + 0] = val.x;
        lt[d * 33 + nch * 4 + 1] = val.y;
        lt[d * 33 + nch * 4 + 2] = val.z;
        lt[d * 33 + nch * 4 + 3] = val.w;
    }
    __syncthreads();

    // np-pairwise partials: thread (n, j) accumulates r_j over i*8+j, both halves.
    {
        #pragma clang fp contract(off)
        int n = t & 31, j = t >> 5;                // j in 0..7
        #pragma unroll
        for (int hf = 0; hf < 2; ++hf) {
            float r = 0.f;
            #pragma unroll
            for (int i = 0; i < 16; ++i) {
                float v = lt[(hf * 128 + i * 8 + j) * 33 + n];
                r += v * v;
            }
            rj[n * 16 + hf * 8 + j] = r;
        }
    }

    // split writes: zh/zl row-major [n][d]
    #pragma unroll
    for (int v = 0; v < 8; ++v) {
        int g = v * 256 + t;
        int n = g >> 6, du = g & 63;
        half4v hv, lv;
        #pragma unroll
        for (int u = 0; u < 4; ++u) {
            float x = lt[(du * 4 + u) * 33 + n] * 2048.0f;   // 2^11 exact
            _Float16 h = (_Float16)x;
            hv[u] = h;
            lv[u] = (_Float16)(x - (float)h);
        }
        size_t off = (size_t)(n0 + n) * 256 + du * 4;
        *(half4v*)(zh + off) = hv;
        *(half4v*)(zl + off) = lv;
    }
    __syncthreads();

    if (t < 64) {                                  // np combine per (n, half)
        #pragma clang fp contract(off)
        int n = t & 31, hf = t >> 5;
        const float* r = &rj[n * 16 + hf * 8];
        hh[hf * 32 + n] = ((r[0] + r[1]) + (r[2] + r[3])) + ((r[4] + r[5]) + (r[6] + r[7]));
    }
    __syncthreads();
    if (t < 32) {
        #pragma clang fp contract(off)
        z2[n0 + t] = hh[t] + hh[32 + t];           // half0 + half1, np order
        rowmin_g[n0 + t] = ~0ull;
    }
}

// ---------- MFMA distance + argmin (8-phase fine-interleaved schedule) ----------
// Block: 256 rows x 256 codes, 512 threads (8 waves, 2M x 4N; wave owns 128x64).
// K loop: 12 tiles of BK=64 over K_eff=768 (A_cat=[zh|zh|zl], B_cat=[ch|cl|ch]).
// Per tile: 4 sub-phases (one per ks=16 slice): {6 ds_read_b128 || stage issue ->
// raw s_barrier -> lgkm -> setprio(1) 8 MFMA setprio(0) -> raw s_barrier}.
// Next tile's B staged in sub-phase 0, A in sub-phase 1 (>=3-phase lead), so the
// single vmcnt(0) at the tile boundary is ~free: loads stay in flight across 7/8
// barriers (T3+T4 counted-wait principle; raw s_barrier does NOT drain vmcnt).
// acc = 2^25*dot; m2 = acc*2^-24 exact; score = (z2+c2) - m2 (matches np fp32).

__device__ __forceinline__ unsigned long long kmin_xor(unsigned long long key, int m) {
    unsigned lo = (unsigned)key, hi = (unsigned)(key >> 32);
    unsigned olo = __shfl_xor(lo, m);
    unsigned ohi = __shfl_xor(hi, m);
    unsigned long long o = ((unsigned long long)ohi << 32) | olo;
    return (o < key) ? o : key;
}

__launch_bounds__(512, 2)
__global__ void argmin_mfma_kernel(const _Float16* __restrict__ zh, const _Float16* __restrict__ zl,
                                   const _Float16* __restrict__ ch, const _Float16* __restrict__ cl,
                                   const float* __restrict__ cb2, const float* __restrict__ z2arr,
                                   unsigned long long* __restrict__ rowmin_g) {
    __shared__ __align__(16) char lds_raw[131072];   // 2 x (A 32KB + B 32KB)
    _Float16* a0 = (_Float16*)lds_raw;
    _Float16* b0 = (_Float16*)(lds_raw + 32768);
    _Float16* a1 = (_Float16*)(lds_raw + 65536);
    _Float16* b1 = (_Float16*)(lds_raw + 98304);

    int t = threadIdx.x;
    // bijective XCD swizzle: 2048 blocks, %8==0 -> each XCD gets a contiguous chunk
    int bid = blockIdx.x;
    int swz = (bid & 7) * 256 + (bid >> 3);
    int r0 = (swz >> 3) * 256;
    int c0 = (swz & 7) * 256;
    int w = t >> 6, lane = t & 63;
    int wm = w >> 2, wn = w & 3;                 // wave -> (row half, col quarter)
    int l31 = lane & 31, l5 = lane >> 5;

    f32x16 acc[4][2];
    #pragma unroll
    for (int i = 0; i < 4; ++i)
        #pragma unroll
        for (int j = 0; j < 2; ++j)
            #pragma unroll
            for (int r = 0; r < 16; ++r) acc[i][j][r] = 0.f;

    float c2v[2];
    #pragma unroll
    for (int j = 0; j < 2; ++j)
        c2v[j] = cb2[c0 + wn * 64 + j * 32 + l31];

    // stage helpers: segment ki in [0,12): A src = (ki<8)?zh:zl, B src = (ki in [4,8))?cl:ch
    auto stage_A = [&](int ki, _Float16* na) {
        int seg = ki >> 2, koff = (ki & 3) * 64;
        const _Float16* asrc = (seg < 2) ? zh : zl;
        #pragma unroll
        for (int v = 0; v < 4; ++v) {
            int p = v * 512 + t;
            int row = p >> 3;
            int ku = (p & 7) ^ (row & 7);        // inverse swizzle on global source
            gload_lds16(asrc + (size_t)(r0 + row) * 256 + koff + ku * 8, na + (size_t)p * 8);
        }
    };
    auto stage_B = [&](int ki, _Float16* nb) {
        int seg = ki >> 2, koff = (ki & 3) * 64;
        const _Float16* bsrc = (seg == 1) ? cl : ch;
        #pragma unroll
        for (int v = 0; v < 4; ++v) {
            int p = v * 512 + t;
            int row = p >> 3;
            int ku = (p & 7) ^ (row & 7);
            gload_lds16(bsrc + (size_t)(c0 + row) * 256 + koff + ku * 8, nb + (size_t)p * 8);
        }
    };

    // one K-tile = 4 sub-phases; stages next tile (nki) into na/nb when ds=true
    auto tile4 = [&](const _Float16* la, const _Float16* lb, _Float16* na, _Float16* nb,
                     int nki, bool ds) {
        #pragma unroll
        for (int ks = 0; ks < 4; ++ks) {
            __builtin_amdgcn_sched_barrier(0);   // pin reads after previous barrier
            half8 af[4], bf[2];
            #pragma unroll
            for (int i = 0; i < 4; ++i) {
                int row = wm * 128 + i * 32 + l31;
                int ku  = (ks * 2 + l5) ^ (row & 7);
                af[i] = *(const half8*)(la + row * 64 + ku * 8);
            }
            #pragma unroll
            for (int j = 0; j < 2; ++j) {
                int row = wn * 64 + j * 32 + l31;
                int ku  = (ks * 2 + l5) ^ (row & 7);
                bf[j] = *(const half8*)(lb + row * 64 + ku * 8);
            }
            if (ds && ks == 0) stage_B(nki, nb); // B needed first next tile: 4-phase lead
            if (ds && ks == 1) stage_A(nki, na); // 3-phase lead
            __builtin_amdgcn_sched_barrier(0);
            __builtin_amdgcn_s_barrier();        // raw: does NOT drain vmcnt
            __builtin_amdgcn_s_setprio(1);
            #pragma unroll
            for (int i = 0; i < 4; ++i)
                #pragma unroll
                for (int j = 0; j < 2; ++j)
                    acc[i][j] = __builtin_amdgcn_mfma_f32_32x32x16_f16(af[i], bf[j], acc[i][j], 0, 0, 0);
            __builtin_amdgcn_s_setprio(0);
            __builtin_amdgcn_sched_barrier(0);
            if (ks == 3) {
                // own stage loads (issued >=3 phases ago) must land before anyone
                // reads the next buffer; barrier below publishes to all waves.
                // "memory" clobber also blocks cross-tile LDS-read CSE.
                asm volatile("s_waitcnt vmcnt(0)" ::: "memory");
            }
            __builtin_amdgcn_s_barrier();
        }
    };

    // prologue: stage tile 0, full drain
    stage_B(0, b0);
    stage_A(0, a0);
    __syncthreads();

    #pragma unroll 1
    for (int kp = 0; kp < 6; ++kp) {
        tile4(a0, b0, a1, b1, 2 * kp + 1, true);     // consume even tile, stage odd
        tile4(a1, b1, a0, b0, 2 * kp + 2, kp < 5);   // consume odd tile, stage even
    }
    __syncthreads();                                  // before LDS reuse as scratch

    // Epilogue. D mapping (32x32): col=lane&31, row=(reg&3)+8*(reg>>2)+4*(lane>>5).
    // Phase 1: lane j-min -> xor16 -> xor8 pair-mins -> 8 keys/row/wave into LDS.
    unsigned long long* scratch = (unsigned long long*)lds_raw;      // 256 x 34 u64
    #pragma unroll
    for (int i = 0; i < 4; ++i) {
        #pragma unroll
        for (int rg = 0; rg < 16; ++rg) {
            int rowoff = (rg & 3) + 8 * (rg >> 2) + 4 * l5;
            int m = wm * 128 + i * 32 + rowoff;
            float zz = z2arr[r0 + m];
            unsigned long long key = ~0ull;
            #pragma unroll
            for (int j = 0; j < 2; ++j) {
                float sc = (zz + c2v[j]) - acc[i][j][rg] * (1.0f / 16777216.0f);
                unsigned long long k2 = ((unsigned long long)__float_as_uint(sc) << 32)
                                      | (unsigned)(c0 + wn * 64 + j * 32 + l31);
                key = (k2 < key) ? k2 : key;      // scores > 0: raw bits orderable
            }
            key = kmin_xor(key, 16);              // stays within 32-lane m-group
            key = kmin_xor(key, 8);
            if (l31 < 8) scratch[m * 34 + wn * 8 + l31] = key;
        }
    }
    __syncthreads();
    // Phase 2: one thread per row reduces its 32 keys, one global atomic per row.
    if (t < 256) {
        const ulonglong2* srow = (const ulonglong2*)(scratch + t * 34);
        unsigned long long best = ~0ull;
        #pragma unroll
        for (int s = 0; s < 16; ++s) {
            ulonglong2 p = srow[s];
            if (p.x < best) best = p.x;
            if (p.y < best) best = p.y;
        }
        atomicMin(&rowmin_g[r0 + t], best);
    }
}

// ---------- gather q, SSE, histogram ----------
__global__ void gather_kernel(const float* __restrict__ z, const float* __restrict__ cb,
                              const unsigned long long* __restrict__ rowmin_g,
                              float* __restrict__ qout,
                              float* __restrict__ sse, int* __restrict__ counts) {
    int t = threadIdx.x;
    int si = t & 63, dg = t >> 6;
    int n = blockIdx.x * 64 + si;
    int idx = (int)(rowmin_g[n] & 0xFFFFFFFFull);
    int b = n >> 12, s = n & 4095;
    const float* zb = z + (size_t)b * DHW + s;
    float*       qb = qout + (size_t)b * DHW + s;
    const float4* crow = (const float4*)(cb + (size_t)idx * D_DIM + dg * 64);
    float acc = 0.f;
    #pragma unroll
    for (int dd4 = 0; dd4 < 16; ++dd4) {
        float4 q4 = crow[dd4];
        float qv[4] = {q4.x, q4.y, q4.z, q4.w};
        #pragma unroll
        for (int u = 0; u < 4; ++u) {
            int d = dg * 64 + dd4 * 4 + u;
            float zv = zb[(size_t)d * HW];
            qb[(size_t)d * HW] = qv[u];
            float df = zv - qv[u];
            acc += df * df;
        }
    }
    #pragma unroll
    for (int off = 32; off > 0; off >>= 1) acc += __shfl_down(acc, off, 64);
    if ((t & 63) == 0) atomicAdd(sse, acc);
    if (dg == 0) atomicAdd(&counts[idx], 1);
}

__global__ void finalize_kernel(const float* __restrict__ sse, const int* __restrict__ counts,
                                float* __restrict__ out) {
    int t = threadIdx.x;
    float mse = *sse * (1.0f / 16777216.0f);   // /(N*D)
    if (t == 0) {
        out[16777216] = mse * 1.25f;  // loss
        out[16777217] = mse;          // codebook_loss
        out[16777218] = mse;          // commitment_loss
    }
    for (int i = t; i < 2048; i += 256) out[16777219 + i] = (float)counts[i];
}

extern "C" void kernel_launch(void* const* d_in, const int* in_sizes, int n_in,
                              void* d_out, int out_size, void* d_ws, size_t ws_size,
                              hipStream_t stream) {
    const float* z  = (const float*)d_in[0];
    const float* cb = (const float*)d_in[1];
    float* out = (float*)d_out;
    float* ws  = (float*)d_ws;

    float* cb2    = ws;                                    // [0,2048)
    int*   counts = (int*)(ws + 2048);                     // [2048,4096)
    float* sse    = ws + 4096;                             // [4096]
    float* z2     = ws + 4352;                             // [4352,69888)
    unsigned long long* rowmin_g = (unsigned long long*)(ws + 69888);  // 512 KB
    _Float16* ch  = (_Float16*)(ws + 200960);              // 1 MB
    _Float16* cl  = (_Float16*)(ws + 463104);              // 1 MB

    _Float16* zzh = (_Float16*)d_out;                      // 32 MB (overwritten by q later)
    _Float16* zzl = zzh + 16777216;                        // 32 MB

    cbnorm_zero_kernel<<<8, 256, 0, stream>>>(cb, cb2, counts, sse);
    split_c_kernel<<<512, 256, 0, stream>>>(cb, ch, cl);
    fused_z_kernel<<<2048, 256, 0, stream>>>(z, zzh, zzl, z2, rowmin_g);
    argmin_mfma_kernel<<<2048, 512, 0, stream>>>(zzh, zzl, ch, cl, cb2, z2, rowmin_g);
    gather_kernel<<<1024, 256, 0, stream>>>(z, cb, rowmin_g, out, sse, counts);
    finalize_kernel<<<1, 256, 0, stream>>>(sse, counts, out);
}

// Round 4
// 453.855 us; speedup vs baseline: 1.0935x; 1.0935x over previous
//
#include <hip/hip_runtime.h>

#define N_TOT 65536
#define K_CB  2048
#define D_DIM 256
#define HW    4096       // H*W
#define DHW   1048576    // D*H*W

typedef _Float16 half8 __attribute__((ext_vector_type(8)));
typedef _Float16 half4v __attribute__((ext_vector_type(4)));
typedef float f32x16 __attribute__((ext_vector_type(16)));

// ws layout (4-byte element offsets):
//   cb2      [0, 2048)          float (np-pairwise ||c_k||^2)
//   counts   [2048, 4096)       int
//   sse      [4096]             float
//   z2       [4352, 69888)      float (np-pairwise ||z_n||^2)
//   rowmin_g [69888, 200960)    u64 x 65536
//   c_hi     [200960, 463104)   fp16 x 524288  (codebook * 2^14, hi)
//   c_lo     [463104, 725248)   fp16 x 524288  (lo)
// z splits live in d_out[0..16777216) floats (overwritten later by q):
//   z_hi = (fp16*)d_out  [65536][256] row-major, z * 2^11 hi;  z_lo follows.

__device__ __forceinline__ void gload_lds16(const void* g, void* l) {
    __builtin_amdgcn_global_load_lds((const __attribute__((address_space(1))) void*)g,
                                     (__attribute__((address_space(3))) void*)l, 16, 0, 0);
}

// ---------- codebook norms (np-pairwise, verified exact) + zero counts/sse ----------
__device__ __forceinline__ float pw128_sq(const float* __restrict__ base, int stride) {
    #pragma clang fp contract(off)
    float r[8];
    #pragma unroll
    for (int j = 0; j < 8; ++j) { float v = base[j * stride]; r[j] = v * v; }
    for (int i = 8; i < 128; i += 8) {
        #pragma unroll
        for (int j = 0; j < 8; ++j) { float v = base[(i + j) * stride]; r[j] += v * v; }
    }
    return ((r[0] + r[1]) + (r[2] + r[3])) + ((r[4] + r[5]) + (r[6] + r[7]));
}

__global__ void cbnorm_zero_kernel(const float* __restrict__ cb, float* __restrict__ cb2,
                                   int* __restrict__ counts, float* __restrict__ sse) {
    #pragma clang fp contract(off)
    int k = blockIdx.x * 256 + threadIdx.x;
    const float* row = cb + (size_t)k * D_DIM;
    cb2[k] = pw128_sq(row, 1) + pw128_sq(row + 128, 1);
    counts[k] = 0;
    if (k == 0) *sse = 0.f;
}

__global__ void split_c_kernel(const float* __restrict__ cb,
                               _Float16* __restrict__ ch, _Float16* __restrict__ cl) {
    int e = (blockIdx.x * 256 + threadIdx.x) * 4;
    float4 v = *(const float4*)(cb + e);
    float xs[4] = {v.x, v.y, v.z, v.w};
    half4v hh, hl;
    #pragma unroll
    for (int u = 0; u < 4; ++u) {
        float x = xs[u] * 16384.0f;                  // 2^14 exact
        _Float16 hv = (_Float16)x;
        hh[u] = hv;
        hl[u] = (_Float16)(x - (float)hv);           // exact sub, then RTNE
    }
    *(half4v*)(ch + e) = hh;
    *(half4v*)(cl + e) = hl;
}

// ---------- fused: z transpose+split, np-exact z2, rowmin_g init ----------
// Block: 32 rows x 256 d. 2048 blocks x 256 threads.
__global__ void fused_z_kernel(const float* __restrict__ z,
                               _Float16* __restrict__ zh, _Float16* __restrict__ zl,
                               float* __restrict__ z2,
                               unsigned long long* __restrict__ rowmin_g) {
    __shared__ __align__(16) float lt[256 * 33];   // lt[d][n], pad stride 33
    __shared__ float rj[512];                      // [n(32)][half(2)][j(8)]
    __shared__ float hh[64];                       // [half(2)][n(32)]
    int t = threadIdx.x;
    int n0 = blockIdx.x * 32;
    int b = n0 >> 12, s0 = n0 & 4095;
    const float* zb = z + (size_t)b * DHW + s0;

    #pragma unroll
    for (int v = 0; v < 8; ++v) {                  // 2048 float4 loads
        int f = v * 256 + t;
        int d = f >> 3, nch = f & 7;
        float4 val = *(const float4*)(zb + (size_t)d * HW + nch * 4);
        lt[d * 33 + nch * 4 + 0] = val.x;
        lt[d * 33 + nch * 4 + 1] = val.y;
        lt[d * 33 + nch * 4 + 2] = val.z;
        lt[d * 33 + nch * 4 + 3] = val.w;
    }
    __syncthreads();

    // np-pairwise partials: thread (n, j) accumulates r_j over i*8+j, both halves.
    {
        #pragma clang fp contract(off)
        int n = t & 31, j = t >> 5;                // j in 0..7
        #pragma unroll
        for (int hf = 0; hf < 2; ++hf) {
            float r = 0.f;
            #pragma unroll
            for (int i = 0; i < 16; ++i) {
                float v = lt[(hf * 128 + i * 8 + j) * 33 + n];
                r += v * v;
            }
            rj[n * 16 + hf * 8 + j] = r;
        }
    }

    // split writes: zh/zl row-major [n][d]
    #pragma unroll
    for (int v = 0; v < 8; ++v) {
        int g = v * 256 + t;
        int n = g >> 6, du = g & 63;
        half4v hv, lv;
        #pragma unroll
        for (int u = 0; u < 4; ++u) {
            float x = lt[(du * 4 + u) * 33 + n] * 2048.0f;   // 2^11 exact
            _Float16 h = (_Float16)x;
            hv[u] = h;
            lv[u] = (_Float16)(x - (float)h);
        }
        size_t off = (size_t)(n0 + n) * 256 + du * 4;
        *(half4v*)(zh + off) = hv;
        *(half4v*)(zl + off) = lv;
    }
    __syncthreads();

    if (t < 64) {                                  // np combine per (n, half)
        #pragma clang fp contract(off)
        int n = t & 31, hf = t >> 5;
        const float* r = &rj[n * 16 + hf * 8];
        hh[hf * 32 + n] = ((r[0] + r[1]) + (r[2] + r[3])) + ((r[4] + r[5]) + (r[6] + r[7]));
    }
    __syncthreads();
    if (t < 32) {
        #pragma clang fp contract(off)
        z2[n0 + t] = hh[t] + hh[32 + t];           // half0 + half1, np order
        rowmin_g[n0 + t] = ~0ull;
    }
}

// ---------- MFMA distance + argmin (occupancy-first: 4 blocks/CU) ----------
// Block: 128 rows x 128 codes, 256 threads (4 waves, 2M x 2N; wave owns 64x64,
// acc[2][2] = 64 acc-regs -> ~110 regs/wave -> 4 waves/SIMD, 4 blocks/CU).
// K loop: 12 tiles of BK=64 over K_eff=768 (A_cat=[zh|zh|zl], B_cat=[ch|cl|ch]).
// m97-simple per tile: {sync; stage 32KB via global_load_lds; sync(drains); compute}.
// Latency hiding comes from 4 INDEPENDENT blocks per CU (m114 inter-block overlap),
// not intra-block scheduling (proven null at 2 waves/SIMD in rounds 1-2).
// acc = 2^25*dot; m2 = acc*2^-24 exact; score = (z2+c2) - m2 (matches np fp32).

__device__ __forceinline__ unsigned long long kmin_xor(unsigned long long key, int m) {
    unsigned lo = (unsigned)key, hi = (unsigned)(key >> 32);
    unsigned olo = __shfl_xor(lo, m);
    unsigned ohi = __shfl_xor(hi, m);
    unsigned long long o = ((unsigned long long)ohi << 32) | olo;
    return (o < key) ? o : key;
}

__launch_bounds__(256, 4)
__global__ void argmin_mfma_kernel(const _Float16* __restrict__ zh, const _Float16* __restrict__ zl,
                                   const _Float16* __restrict__ ch, const _Float16* __restrict__ cl,
                                   const float* __restrict__ cb2, const float* __restrict__ z2arr,
                                   unsigned long long* __restrict__ rowmin_g) {
    __shared__ __align__(16) char lds_raw[32768];
    _Float16* lds_a = (_Float16*)lds_raw;            // 128 rows x 64 k (16B-unit XOR swizzle)
    _Float16* lds_b = (_Float16*)(lds_raw + 16384);  // 128 codes x 64 k

    int t = threadIdx.x;
    // bijective XCD swizzle: 8192 blocks, 1024 per XCD. Within an XCD chunk,
    // ct (c-tile, 16 of them) is fastest -> the 16 B-panels (3 MB) stay L2-resident;
    // the A-panel (192 KB) is reused across the ct-sweep.
    int bid = blockIdx.x;
    int swz = (bid & 7) * 1024 + (bid >> 3);
    int r0 = (swz >> 4) * 128;
    int c0 = (swz & 15) * 128;
    int w = t >> 6, lane = t & 63;
    int wm = w >> 1, wn = w & 1;                 // wave -> (row half, col half)
    int l31 = lane & 31, l5 = lane >> 5;

    f32x16 acc[2][2];
    #pragma unroll
    for (int i = 0; i < 2; ++i)
        #pragma unroll
        for (int j = 0; j < 2; ++j)
            #pragma unroll
            for (int r = 0; r < 16; ++r) acc[i][j][r] = 0.f;

    float c2v[2];
    #pragma unroll
    for (int j = 0; j < 2; ++j)
        c2v[j] = cb2[c0 + wn * 64 + j * 32 + l31];

    for (int ki = 0; ki < 12; ++ki) {
        int seg  = ki >> 2;
        int koff = (ki & 3) * 64;
        const _Float16* asrc = (seg < 2) ? zh : zl;
        const _Float16* bsrc = (seg == 1) ? cl : ch;
        __syncthreads();                             // prev compute done: safe to overwrite
        #pragma unroll
        for (int v = 0; v < 4; ++v) {                // A: 1024 16B-units
            int p = v * 256 + t;
            int row = p >> 3;
            int ku = (p & 7) ^ (row & 7);            // inverse swizzle on global source
            gload_lds16(asrc + (size_t)((r0 + row) * 256 + koff + ku * 8), lds_a + p * 8);
        }
        #pragma unroll
        for (int v = 0; v < 4; ++v) {                // B: 1024 16B-units
            int p = v * 256 + t;
            int row = p >> 3;
            int ku = (p & 7) ^ (row & 7);
            gload_lds16(bsrc + (size_t)((c0 + row) * 256 + koff + ku * 8), lds_b + p * 8);
        }
        __syncthreads();                             // implicit vmcnt(0) drain: tile ready
        #pragma unroll
        for (int ks = 0; ks < 4; ++ks) {             // 4 k-steps of 16
            half8 af[2], bf[2];
            #pragma unroll
            for (int i = 0; i < 2; ++i) {
                int row = wm * 64 + i * 32 + l31;
                int ku  = (ks * 2 + l5) ^ (row & 7);
                af[i] = *(const half8*)(lds_a + row * 64 + ku * 8);
            }
            #pragma unroll
            for (int j = 0; j < 2; ++j) {
                int row = wn * 64 + j * 32 + l31;
                int ku  = (ks * 2 + l5) ^ (row & 7);
                bf[j] = *(const half8*)(lds_b + row * 64 + ku * 8);
            }
            #pragma unroll
            for (int i = 0; i < 2; ++i)
                #pragma unroll
                for (int j = 0; j < 2; ++j)
                    acc[i][j] = __builtin_amdgcn_mfma_f32_32x32x16_f16(af[i], bf[j], acc[i][j], 0, 0, 0);
        }
    }
    __syncthreads();                                 // protect LDS reuse as scratch

    // Epilogue. D mapping (32x32): col=lane&31, row=(reg&3)+8*(reg>>2)+4*(lane>>5).
    // Phase 1: lane j-min -> xor16 -> xor8 pair-mins -> 8 keys/row/wave into LDS.
    unsigned long long* scratch = (unsigned long long*)lds_raw;      // 128 x 18 u64
    #pragma unroll
    for (int i = 0; i < 2; ++i) {
        #pragma unroll
        for (int rg = 0; rg < 16; ++rg) {
            int rowoff = (rg & 3) + 8 * (rg >> 2) + 4 * l5;
            int m = wm * 64 + i * 32 + rowoff;
            float zz = z2arr[r0 + m];
            unsigned long long key = ~0ull;
            #pragma unroll
            for (int j = 0; j < 2; ++j) {
                float sc = (zz + c2v[j]) - acc[i][j][rg] * (1.0f / 16777216.0f);
                unsigned long long k2 = ((unsigned long long)__float_as_uint(sc) << 32)
                                      | (unsigned)(c0 + wn * 64 + j * 32 + l31);
                key = (k2 < key) ? k2 : key;      // scores > 0: raw bits orderable
            }
            key = kmin_xor(key, 16);              // stays within 32-lane m-group
            key = kmin_xor(key, 8);
            if (l31 < 8) scratch[m * 18 + wn * 8 + l31] = key;
        }
    }
    __syncthreads();
    // Phase 2: one thread per row reduces its 16 keys, one global atomic per row.
    if (t < 128) {
        const ulonglong2* srow = (const ulonglong2*)(scratch + t * 18);
        unsigned long long best = ~0ull;
        #pragma unroll
        for (int s = 0; s < 8; ++s) {
            ulonglong2 p = srow[s];
            if (p.x < best) best = p.x;
            if (p.y < best) best = p.y;
        }
        atomicMin(&rowmin_g[r0 + t], best);
    }
}

// ---------- gather q, SSE, histogram ----------
__global__ void gather_kernel(const float* __restrict__ z, const float* __restrict__ cb,
                              const unsigned long long* __restrict__ rowmin_g,
                              float* __restrict__ qout,
                              float* __restrict__ sse, int* __restrict__ counts) {
    int t = threadIdx.x;
    int si = t & 63, dg = t >> 6;
    int n = blockIdx.x * 64 + si;
    int idx = (int)(rowmin_g[n] & 0xFFFFFFFFull);
    int b = n >> 12, s = n & 4095;
    const float* zb = z + (size_t)b * DHW + s;
    float*       qb = qout + (size_t)b * DHW + s;
    const float4* crow = (const float4*)(cb + (size_t)idx * D_DIM + dg * 64);
    float acc = 0.f;
    #pragma unroll
    for (int dd4 = 0; dd4 < 16; ++dd4) {
        float4 q4 = crow[dd4];
        float qv[4] = {q4.x, q4.y, q4.z, q4.w};
        #pragma unroll
        for (int u = 0; u < 4; ++u) {
            int d = dg * 64 + dd4 * 4 + u;
            float zv = zb[(size_t)d * HW];
            qb[(size_t)d * HW] = qv[u];
            float df = zv - qv[u];
            acc += df * df;
        }
    }
    #pragma unroll
    for (int off = 32; off > 0; off >>= 1) acc += __shfl_down(acc, off, 64);
    if ((t & 63) == 0) atomicAdd(sse, acc);
    if (dg == 0) atomicAdd(&counts[idx], 1);
}

__global__ void finalize_kernel(const float* __restrict__ sse, const int* __restrict__ counts,
                                float* __restrict__ out) {
    int t = threadIdx.x;
    float mse = *sse * (1.0f / 16777216.0f);   // /(N*D)
    if (t == 0) {
        out[16777216] = mse * 1.25f;  // loss
        out[16777217] = mse;          // codebook_loss
        out[16777218] = mse;          // commitment_loss
    }
    for (int i = t; i < 2048; i += 256) out[16777219 + i] = (float)counts[i];
}

extern "C" void kernel_launch(void* const* d_in, const int* in_sizes, int n_in,
                              void* d_out, int out_size, void* d_ws, size_t ws_size,
                              hipStream_t stream) {
    const float* z  = (const float*)d_in[0];
    const float* cb = (const float*)d_in[1];
    float* out = (float*)d_out;
    float* ws  = (float*)d_ws;

    float* cb2    = ws;                                    // [0,2048)
    int*   counts = (int*)(ws + 2048);                     // [2048,4096)
    float* sse    = ws + 4096;                             // [4096]
    float* z2     = ws + 4352;                             // [4352,69888)
    unsigned long long* rowmin_g = (unsigned long long*)(ws + 69888);  // 512 KB
    _Float16* ch  = (_Float16*)(ws + 200960);              // 1 MB
    _Float16* cl  = (_Float16*)(ws + 463104);              // 1 MB

    _Float16* zzh = (_Float16*)d_out;                      // 32 MB (overwritten by q later)
    _Float16* zzl = zzh + 16777216;                        // 32 MB

    cbnorm_zero_kernel<<<8, 256, 0, stream>>>(cb, cb2, counts, sse);
    split_c_kernel<<<512, 256, 0, stream>>>(cb, ch, cl);
    fused_z_kernel<<<2048, 256, 0, stream>>>(z, zzh, zzl, z2, rowmin_g);
    argmin_mfma_kernel<<<8192, 256, 0, stream>>>(zzh, zzl, ch, cl, cb2, z2, rowmin_g);
    gather_kernel<<<1024, 256, 0, stream>>>(z, cb, rowmin_g, out, sse, counts);
    finalize_kernel<<<1, 256, 0, stream>>>(sse, counts, out);
}